// Round 5
// baseline (1629.958 us; speedup 1.0000x reference)
//
#include <hip/hip_runtime.h>
#include <hip/hip_bf16.h>

typedef short s16x8 __attribute__((ext_vector_type(8)));
typedef float f32x4 __attribute__((ext_vector_type(4)));

#define B_  128
#define T_  256
#define D_  1024

// workspace layout
#define WPACK_BYTES (6144u * 2048u)            // bf16 [6144 cols][1024 k], col = gate*1024 + d
#define HBUF_BYTES  (128u * 1024u * 2u)        // h state, bf16, fragment-ordered (256 KB)
#define HA_OFF      (WPACK_BYTES)
#define HB_OFF      (HA_OFF + HBUF_BYTES)
#define SLOTS_OFF   (HB_OFF + HBUF_BYTES)      // 256 dense u32 slots (4 teams x 64)
#define WS_NEEDED   (SLOTS_OFF + 1024u)

static __device__ __forceinline__ float sigm_f(float x) {
  float e = __builtin_amdgcn_exp2f(-1.4426950408889634f * x);
  return __builtin_amdgcn_rcpf(1.0f + e);
}
static __device__ __forceinline__ float tanh_f(float x) {
  float e = __builtin_amdgcn_exp2f(-2.8853900817779268f * x);
  return 2.0f * __builtin_amdgcn_rcpf(1.0f + e) - 1.0f;
}
static __device__ __forceinline__ unsigned short f2bf(float f) {
  return __builtin_bit_cast(unsigned short, __float2bfloat16(f));
}
// coherent (L1+L2-bypassing) 16B load/store: h state never lives in any cache,
// so no acquire/release fences (buffer_inv / buffer_wbl2) are needed anywhere.
// NOTE: asm-load outputs complete ASYNCHRONOUSLY — every consumer must be
// preceded by an explicit s_waitcnt vmcnt + sched_barrier (R4 lesson).
static __device__ __forceinline__ s16x8 ldg_coh(const char* p) {
  s16x8 v;
  asm volatile("global_load_dwordx4 %0, %1, off sc0 sc1" : "=v"(v) : "v"(p));
  return v;
}
static __device__ __forceinline__ void stg_coh(char* p, s16x8 v) {
  asm volatile("global_store_dwordx4 %0, %1, off sc0 sc1" :: "v"(p), "v"(v) : "memory");
}
// fragment-ordered h layout: byte offset of element (b, k).
// frag (rg, kk) = rows [rg*16,+16) x k [kk*32,+32) = 1 KB, lane-linear:
// lane l = ks*16 + r holds bytes [l*16, l*16+16) = k0 0..7 of (r, ks).
static __device__ __forceinline__ unsigned hoff(int b, int k) {
  unsigned rg = (unsigned)b >> 4, r = (unsigned)b & 15u;
  unsigned kk = (unsigned)k >> 5, ks = ((unsigned)k >> 3) & 3u, k0 = (unsigned)k & 7u;
  return (rg * 32u + kk) * 1024u + (ks * 16u + r) * 16u + k0 * 2u;
}

// ---------------- prepass: pack weights (bf16), pack x0, init slots ----------------
extern "C" __global__ __launch_bounds__(256)
void gru_prepass(const float* __restrict__ x, const float* __restrict__ Wk,
                 const float* __restrict__ Wr, float* __restrict__ out,
                 char* __restrict__ ws) {
  const int W = blockIdx.x, tid = threadIdx.x;
  if (W < 3072) {
    const int v = W * 4 + (tid >> 6);
    const int lane = tid & 63;
    const int cb = v % 96, gk = v / 96;           // cb: 64-col block, gk: 8-k granule
    const int c = cb * 64 + lane;
    const float* src = (c < 3072) ? (Wk + c) : (Wr + (c - 3072));
    s16x8 pk;
#pragma unroll
    for (int j = 0; j < 8; ++j) {
      float val = src[(size_t)(gk * 8 + j) * 3072u];   // coalesced across lanes
      pk[j] = (short)f2bf(val);
    }
    *(s16x8*)(ws + (size_t)c * 2048u + (unsigned)gk * 16u) = pk;
  } else if (W < 3200) {
    // pack x0 -> hA (fragment layout, bf16) and copy out[:,0,:]
    const int b = W - 3072;
    const int k4 = tid * 4;
    float4 v = *(const float4*)(x + (size_t)b * D_ + k4);
    ushort4 u;
    u.x = f2bf(v.x); u.y = f2bf(v.y); u.z = f2bf(v.z); u.w = f2bf(v.w);
    *(ushort4*)(ws + HA_OFF + hoff(b, k4)) = u;
    *(float4*)(out + ((size_t)b * T_) * D_ + k4) = v;
  } else {
    if (tid < 256) ((unsigned*)(ws + SLOTS_OFF))[tid] = 0u;
  }
}

// ---------------- persistent GRU kernel: 256 wgs (1/CU), 255 steps ----------------
// 4 independent teams of 64 wgs; team tau owns rows [tau*32, +32).
// wg (tau, db) owns d-cols [db*16, +16). Waves: kh = K-half, nh = d-col-half (8 cols).
extern "C" __global__ __launch_bounds__(256, 1)
void gru_main(const float* __restrict__ bias, float* __restrict__ out,
              char* __restrict__ ws) {
  // 64 KB: A-tile staging (64 frags x 1 KB). Reduce (12 KB) + stag (1 KB) alias
  // the front of it; extra barriers below make the phases disjoint.
  __shared__ __align__(16) char ldsA[64 * 1024];
  f32x4* lds_red = (f32x4*)ldsA;
  unsigned short* stag = (unsigned short*)(ldsA + 12 * 1024);

  const int tid = threadIdx.x;
  const int w = tid >> 6, lane = tid & 63;
  const int kh = w & 1;                   // K half (reduce partner = w^1)
  const int nh = w >> 1;                  // d-col half
  const int tau = blockIdx.x >> 6;        // team (row-block of 32)
  const int db  = blockIdx.x & 63;        // d-block (16 cols)
  const int d0w = db * 16 + nh * 8;       // this wave's 8 d-cols

  char* hA = ws + HA_OFF;
  char* hB = ws + HB_OFF;
  unsigned* slots = (unsigned*)(ws + SLOTS_OFF);

  // ---- load this wave's 48 B-fragments into registers; static for all 255 steps ----
  s16x8 breg[3][16];
#pragma unroll
  for (int nt = 0; nt < 3; ++nt) {
    const int lc = nt * 16 + (lane & 15);
    const int c = (lc >> 3) * 1024 + d0w + (lc & 7);
    const char* colp = ws + (size_t)c * 2048u + (unsigned)((lane >> 4) * 16);
#pragma unroll
    for (int i = 0; i < 16; ++i) {
      const int kk = kh * 16 + i;
      breg[nt][i] = *(const s16x8*)(colp + (unsigned)kk * 64u);
    }
  }

  const int dl = lane & 7;
  const float bz = bias[d0w + dl];
  const float br = bias[1024 + d0w + dl];
  const float bh = bias[2048 + d0w + dl];
  const int hi = (lane >> 3) & 1;     // which gate-triple this lane's C columns hold
  const int d = d0w + dl;
  // team-local A base: frag (rg=2*tau+rg2, kk) sits at tau*64KB + (rg2*32+kk)*1KB
  const unsigned teamA = (unsigned)tau * 65536u;
  // this wave's h-store frag: rg = 2*tau+kh, kk = db>>1, ks = 2*(db&1)+nh
  const unsigned hstore_off = teamA + (unsigned)(kh * 32 + (db >> 1)) * 1024u
                            + (unsigned)(2 * (db & 1) + nh) * 256u;

  float hprev[4] = {0.f, 0.f, 0.f, 0.f};  // h_{t-1} for this lane's (brow, d)

  for (int t = 1; t < 256; ++t) {
    const char* hs = (t & 1) ? hA : hB;   // t=1 reads hA = packed x0
    char*       hd = (t & 1) ? hB : hA;

    // ---- readiness: all 64 team producers posted step t-1 (every wave scans) ----
    if (t > 1) {
      const unsigned* sl = slots + tau * 64 + lane;
      int guard = 0;
      while (!__all(__hip_atomic_load(sl, __ATOMIC_RELAXED, __HIP_MEMORY_SCOPE_AGENT)
                    >= (unsigned)(t - 1))) {
        __builtin_amdgcn_s_sleep(1);
        if (++guard > (1 << 22)) break;   // fail loudly instead of hanging
      }
    }

    // ---- cooperative A staging: wave loads frags [w*16, +16) -> LDS ----
    {
      s16x8 tmp[16];
      const char* gb = hs + teamA + (unsigned)(w * 16) * 1024u + (unsigned)(lane * 16);
#pragma unroll
      for (int j = 0; j < 16; ++j) tmp[j] = ldg_coh(gb + (unsigned)j * 1024u);
      // R4 bugfix: asm-load results are async — drain vmcnt BEFORE the LDS
      // writes, and pin ordering (rule #18) so ds_write can't hoist above it.
      asm volatile("s_waitcnt vmcnt(0)" ::: "memory");
      __builtin_amdgcn_sched_barrier(0);
      char* lb = ldsA + (unsigned)(w * 16) * 1024u + (unsigned)(lane * 16);
#pragma unroll
      for (int j = 0; j < 16; ++j) *(s16x8*)(lb + (unsigned)j * 1024u) = tmp[j];
    }
    __syncthreads();                                   // A tile ready

    // ---- A fragments from LDS + MFMA (both m-tiles, own K-half) ----
    s16x8 a0[16], a1[16];
    {
      const char* l0 = ldsA + (unsigned)(kh * 16) * 1024u + (unsigned)(lane * 16);
#pragma unroll
      for (int i = 0; i < 16; ++i) {
        a0[i] = *(const s16x8*)(l0 + (unsigned)i * 1024u);
        a1[i] = *(const s16x8*)(l0 + 32768u + (unsigned)i * 1024u);
      }
    }
    f32x4 acc0[3], acc1[3];
#pragma unroll
    for (int nt = 0; nt < 3; ++nt) {
      acc0[nt] = (f32x4){0.f, 0.f, 0.f, 0.f};
      acc1[nt] = (f32x4){0.f, 0.f, 0.f, 0.f};
    }
#pragma unroll
    for (int i = 0; i < 16; ++i)
#pragma unroll
      for (int nt = 0; nt < 3; ++nt) {
        acc0[nt] = __builtin_amdgcn_mfma_f32_16x16x32_bf16(a0[i], breg[nt][i], acc0[nt], 0, 0, 0);
        acc1[nt] = __builtin_amdgcn_mfma_f32_16x16x32_bf16(a1[i], breg[nt][i], acc1[nt], 0, 0, 0);
      }
    __syncthreads();   // all A-reads done: safe to overwrite aliased red region

    // ---- cross-wave K reduction: wave owns m-tile kh, partner w^1 has other half ----
#pragma unroll
    for (int nt = 0; nt < 3; ++nt)
      lds_red[(w * 3 + nt) * 64 + lane] = kh ? acc0[nt] : acc1[nt];
    __syncthreads();
    f32x4 g3[3];
#pragma unroll
    for (int nt = 0; nt < 3; ++nt) {
      f32x4 mine = kh ? acc1[nt] : acc0[nt];
      g3[nt] = mine + lds_red[((w ^ 1) * 3 + nt) * 64 + lane];
    }

    // lane holds gates {2nt+hi}; partner lane^8 holds the complementary triple
    float o0[4], o1[4], o2[4];
#pragma unroll
    for (int j = 0; j < 4; ++j) {
      o0[j] = __shfl_xor(g3[0][j], 8);
      o1[j] = __shfl_xor(g3[1][j], 8);
      o2[j] = __shfl_xor(g3[2][j], 8);
    }

    float hn_v[4];
#pragma unroll
    for (int j = 0; j < 4; ++j) {
      float xz = hi ? o0[j] : g3[0][j];
      float xh = hi ? o1[j] : g3[1][j];
      float hr = hi ? o2[j] : g3[2][j];
      float xr = hi ? g3[0][j] : o0[j];
      float hz = hi ? g3[1][j] : o1[j];
      float hh = hi ? g3[2][j] : o2[j];
      if (t == 1) { hz = 0.f; hr = 0.f; hh = 0.f; }   // h0 = 0: rec-gate matmul is garbage
      float z  = sigm_f(xz + bz + hz);
      float r  = sigm_f(xr + br + hr);
      float hc = tanh_f(xh + bh + r * hh);
      float hn = z * hprev[j] + (1.f - z) * hc;
      hn_v[j] = hn;
      hprev[j] = hn;
      if (hi == 0)                          // stage bf16 h for the wide WT store
        stag[w * 128 + ((lane >> 4) * 4 + j) * 8 + dl] = f2bf(hn);
    }

    if (t < 255) {   // t=255: nobody reads h_255 — skip store/drain/slot
      __syncthreads();
      if (lane < 16) {
        s16x8 pk = *(const s16x8*)&stag[w * 128 + lane * 8];
        stg_coh(hd + hstore_off + (unsigned)(lane * 16), pk);
      }
      asm volatile("s_waitcnt vmcnt(0)" ::: "memory");    // WT stores at coherence point
      __builtin_amdgcn_sched_barrier(0);
      __syncthreads();                                     // all 4 waves drained
      if (tid == 0)
        __hip_atomic_store(&slots[blockIdx.x], (unsigned)t,
                           __ATOMIC_RELAXED, __HIP_MEMORY_SCOPE_AGENT);
    }

    // output stream (read by nobody): nontemporal, overlaps next poll
    if (hi == 1) {
#pragma unroll
      for (int j = 0; j < 4; ++j) {
        const int brow = tau * 32 + kh * 16 + (lane >> 4) * 4 + j;
        __builtin_nontemporal_store(hn_v[j], &out[((size_t)brow * T_ + t) * D_ + d]);
      }
    }
  }
}

extern "C" void kernel_launch(void* const* d_in, const int* in_sizes, int n_in,
                              void* d_out, int out_size, void* d_ws, size_t ws_size,
                              hipStream_t stream) {
  (void)in_sizes; (void)n_in; (void)out_size;
  if (ws_size < WS_NEEDED) return;   // fail loudly via absmax rather than corrupt
  const float* x    = (const float*)d_in[0];
  const float* Wk   = (const float*)d_in[1];
  const float* Wr   = (const float*)d_in[2];
  const float* bias = (const float*)d_in[3];
  float* out = (float*)d_out;
  char*  ws  = (char*)d_ws;

  hipLaunchKernelGGL(gru_prepass, dim3(3201), dim3(256), 0, stream, x, Wk, Wr, out, ws);
  hipLaunchKernelGGL(gru_main,    dim3(256),  dim3(256), 0, stream, bias, out, ws);
}